// Round 10
// baseline (285.391 us; speedup 1.0000x reference)
//
#include <hip/hip_runtime.h>
#include <hip/hip_bf16.h>
#include <math.h>

#define NN 8192
#define QSCALE (0.125f * 1.44269504088896f)   // fold 0.125 and log2(e) into Q
#define OSZ (8192*64)
#define NSL 16                                 // pass2 output slices

typedef __attribute__((ext_vector_type(8))) short short8;
typedef __attribute__((ext_vector_type(16))) float f32x16;
typedef __attribute__((ext_vector_type(4))) float f32x4;

union W4 { unsigned u[4]; short8 v; };

__device__ inline unsigned short f2bf(float x) {
  union { float f; unsigned u; } t; t.f = x;
  unsigned r = t.u + 0x7fffu + ((t.u >> 16) & 1u);
  return (unsigned short)(r >> 16);
}
__device__ inline unsigned cvtpk(float lo, float hi) {
  unsigned r;
  asm("v_cvt_pk_bf16_f32 %0, %1, %2" : "=v"(r) : "v"(lo), "v"(hi));
  return r;
}
__device__ inline float fexp2(float x) {
  float r;
  asm("v_exp_f32 %0, %1" : "=v"(r) : "v"(x));
  return r;
}
__device__ inline f32x4 ntload4(const float* p) {
  return __builtin_nontemporal_load((const f32x4*)p);
}

// ---------------------------------------------------------------------------
// Kernel 1: Q/K/V/H pre-pack.
//  QP[c8][i][e] = Q[i][c8*8+e]*QSCALE ; KP same for K
//  VP[j8][d][e] = V[j8*8+e][d] (raw) ; HP same for H
// ---------------------------------------------------------------------------
__global__ __launch_bounds__(256) void qkv_kernel(
    const float* __restrict__ X, const float* __restrict__ H,
    const float* __restrict__ Qw, const float* __restrict__ Qb,
    const float* __restrict__ Kw, const float* __restrict__ Kb,
    const float* __restrict__ Vw, const float* __restrict__ Vb,
    const float* __restrict__ bng, const float* __restrict__ bnb,
    const float* __restrict__ bnm, const float* __restrict__ bnv,
    unsigned short* __restrict__ QP, unsigned short* __restrict__ KP,
    unsigned short* __restrict__ VP, unsigned short* __restrict__ HP)
{
  int wid = (blockIdx.x * blockDim.x + threadIdx.x) >> 6; // 0..2047
  int d = threadIdx.x & 63;
  float4 w[16];

  for (int fq = 0; fq < 16; fq++) w[fq] = *(const float4*)(Qw + d*64 + fq*4);
  for (int rr = 0; rr < 4; rr++) {
    int r = wid*4 + rr;
    float a = Qb[d];
    for (int fq = 0; fq < 16; fq++) {
      float4 xv = *(const float4*)(X + r*64 + fq*4);
      a += w[fq].x*xv.x + w[fq].y*xv.y + w[fq].z*xv.z + w[fq].w*xv.w;
    }
    float s = a;
    for (int off = 32; off; off >>= 1) s += __shfl_xor(s, off);
    float mean = s * (1.f/64.f);
    float c = a - mean;
    float s2 = c*c;
    for (int off = 32; off; off >>= 1) s2 += __shfl_xor(s2, off);
    float q = c * rsqrtf(s2*(1.f/64.f) + 1e-5f);
    QP[(d>>3)*65536 + r*8 + (d&7)] = f2bf(q * QSCALE);
  }
  for (int fq = 0; fq < 16; fq++) w[fq] = *(const float4*)(Kw + d*64 + fq*4);
  for (int rr = 0; rr < 4; rr++) {
    int r = wid*4 + rr;
    float a = Kb[d];
    for (int fq = 0; fq < 16; fq++) {
      float4 hv = *(const float4*)(H + r*64 + fq*4);
      a += w[fq].x*hv.x + w[fq].y*hv.y + w[fq].z*hv.z + w[fq].w*hv.w;
    }
    float s = a;
    for (int off = 32; off; off >>= 1) s += __shfl_xor(s, off);
    float mean = s * (1.f/64.f);
    float c = a - mean;
    float s2 = c*c;
    for (int off = 32; off; off >>= 1) s2 += __shfl_xor(s2, off);
    float k = c * rsqrtf(s2*(1.f/64.f) + 1e-5f);
    KP[(d>>3)*65536 + r*8 + (d&7)] = f2bf(k);
  }
  for (int fq = 0; fq < 16; fq++) w[fq] = *(const float4*)(Vw + d*64 + fq*4);
  float bscale = rsqrtf(bnv[d] + 1e-5f) * bng[d];
  for (int rr = 0; rr < 4; rr++) {
    int r = wid*4 + rr;
    float a = Vb[d];
    for (int fq = 0; fq < 16; fq++) {
      float4 hv = *(const float4*)(H + r*64 + fq*4);
      a += w[fq].x*hv.x + w[fq].y*hv.y + w[fq].z*hv.z + w[fq].w*hv.w;
    }
    float v = (a - bnm[d]) * bscale + bnb[d];
    VP[(r>>3)*512 + d*8 + (r&7)] = f2bf(v);
    HP[(r>>3)*512 + d*8 + (r&7)] = f2bf(H[r*64 + d]);
  }
}

// ---------------------------------------------------------------------------
// pass 1 (lean): per-column sums of exp2(s*M). Plain (cached) M loads so the
// L3 is warm with M for pass2. No LDS, no barrier.
// ---------------------------------------------------------------------------
__global__ __launch_bounds__(256) void pass1_kernel(
    const float* __restrict__ M, const unsigned short* __restrict__ QP,
    const unsigned short* __restrict__ KP, float* __restrict__ pd)
{
  int tid = threadIdx.x;
  int wj = (blockIdx.x * blockDim.x + tid) >> 6;  // 0..8191
  int lane = tid & 63;
  int l31 = lane & 31, h = lane >> 5;
  int jb = wj & 255, slice = wj >> 8;             // 256 jb x 32 slices
  int j = jb*32 + l31;

  short8 kb[4];
  for (int m = 0; m < 4; m++)
    kb[m] = *(const short8*)(KP + (2*m + h)*65536 + j*8);

  float Mv[16];
  {
    int i0 = slice*8*32;
#pragma unroll
    for (int r = 0; r < 16; r++) {
      int ir = (r&3) + 8*(r>>2) + 4*h;
      Mv[r] = M[(size_t)(i0 + ir)*NN + j];
    }
  }

  float d0 = 0.f, d1 = 0.f, d2 = 0.f, d3 = 0.f;
  for (int t = 0; t < 8; t++) {
    int i0 = (slice*8 + t) * 32;
    float Mn[16];
    if (t < 7) {
      int i1 = i0 + 32;
#pragma unroll
      for (int r = 0; r < 16; r++) {
        int ir = (r&3) + 8*(r>>2) + 4*h;
        Mn[r] = M[(size_t)(i1 + ir)*NN + j];
      }
    }

    f32x16 acc;
    for (int r = 0; r < 16; r++) acc[r] = 0.f;
    for (int m = 0; m < 4; m++) {
      short8 qa = *(const short8*)(QP + (2*m + h)*65536 + (size_t)(i0 + l31)*8);
      acc = __builtin_amdgcn_mfma_f32_32x32x16_bf16(qa, kb[m], acc, 0, 0, 0);
    }

    d0 += fexp2(acc[0]*Mv[0]) + fexp2(acc[4]*Mv[4]) + fexp2(acc[8]*Mv[8])   + fexp2(acc[12]*Mv[12]);
    d1 += fexp2(acc[1]*Mv[1]) + fexp2(acc[5]*Mv[5]) + fexp2(acc[9]*Mv[9])   + fexp2(acc[13]*Mv[13]);
    d2 += fexp2(acc[2]*Mv[2]) + fexp2(acc[6]*Mv[6]) + fexp2(acc[10]*Mv[10]) + fexp2(acc[14]*Mv[14]);
    d3 += fexp2(acc[3]*Mv[3]) + fexp2(acc[7]*Mv[7]) + fexp2(acc[11]*Mv[11]) + fexp2(acc[15]*Mv[15]);

    if (t < 7) {
#pragma unroll
      for (int r = 0; r < 16; r++) Mv[r] = Mn[r];
    }
  }
  float drun = (d0 + d1) + (d2 + d3);
  drun += __shfl_xor(drun, 32);
  if (lane < 32) pd[(size_t)slice*NN + j] = drun;
}

// ---------------------------------------------------------------------------
// combine: csc[j] = alpha / D_j   (normalization folded into V)
// ---------------------------------------------------------------------------
__global__ __launch_bounds__(256) void combine_kernel(
    const float* __restrict__ pd, float* __restrict__ csc)
{
  int j = blockIdx.x * blockDim.x + threadIdx.x;
  float Dv = 0.f;
  for (int s = 0; s < 32; s++) Dv += pd[(size_t)s*NN + j];
  csc[j] = 0.1f / Dv;
}

// ---------------------------------------------------------------------------
// vscale: VP2[j8][d][e] = VP[j8][d][e] * csc[j8*8+e]  (coalesced short8)
// ---------------------------------------------------------------------------
__global__ __launch_bounds__(256) void vscale_kernel(
    const unsigned short* __restrict__ VP, const float* __restrict__ csc,
    unsigned short* __restrict__ VP2)
{
  int idx = blockIdx.x * blockDim.x + threadIdx.x;   // 0..65535 = (j8, d)
  int j8 = idx >> 6;
  const unsigned short* src = VP + (size_t)idx*8;
  float c[8];
#pragma unroll
  for (int e = 0; e < 8; e++) c[e] = csc[j8*8 + e];
  unsigned short sv[8];
  *(short8*)sv = *(const short8*)src;
  float f[8];
#pragma unroll
  for (int e = 0; e < 8; e++)
    f[e] = __uint_as_float(((unsigned)sv[e]) << 16) * c[e];
  W4 o;
  o.u[0] = cvtpk(f[0], f[1]); o.u[1] = cvtpk(f[2], f[3]);
  o.u[2] = cvtpk(f[4], f[5]); o.u[3] = cvtpk(f[6], f[7]);
  *(short8*)(VP2 + (size_t)idx*8) = o.v;
}

// ---------------------------------------------------------------------------
// pass 2 (LDS-free, barrier-free): out_part = exp2(s*M)@V' + M@H.
// Lane=i swapped GEMM; each lane reads its OWN M row segment directly from
// global (32 rows x 128B full-line utilization per tm). Normalization is
// pre-folded into V' (vscale) -- no colcc, no LDS, no barriers at all.
// Grid = 128 iblk x 16 slices (512 j); WG = 4 waves (iq = wv&1, dh = wv>>1).
// 1-deep M register prefetch across tm.
// ---------------------------------------------------------------------------
__global__ __launch_bounds__(256) void pass2_kernel(
    const float* __restrict__ M, const unsigned short* __restrict__ QP,
    const unsigned short* __restrict__ KP, const unsigned short* __restrict__ VP2,
    const unsigned short* __restrict__ HP, float* __restrict__ opart)
{
  int iblk = blockIdx.x >> 4, slice = blockIdx.x & 15;
  int i0 = iblk * 64;
  int tid = threadIdx.x;
  int lane = tid & 63, wv = tid >> 6;
  int l31 = lane & 31, h = lane >> 5;
  int iq = wv & 1, dh = wv >> 1;
  int i_g = i0 + iq*32 + l31;

  short8 qb[4];
#pragma unroll
  for (int m = 0; m < 4; m++)
    qb[m] = *(const short8*)(QP + (2*m + h)*65536 + (size_t)i_g*8);

  f32x16 oacc;
  for (int r = 0; r < 16; r++) oacc[r] = 0.f;

  // per-lane M row base: this lane's i row, this wave-half's 4-col offset
  const float* mrow = M + (size_t)i_g*NN + slice*512 + 4*h;

  // prefetch tm=0: four float4 at col offsets 0,8,16,24 (+4h)
  f32x4 mc0 = ntload4(mrow);
  f32x4 mc1 = ntload4(mrow + 8);
  f32x4 mc2 = ntload4(mrow + 16);
  f32x4 mc3 = ntload4(mrow + 24);

  for (int tm = 0; tm < 16; tm++) {
    int jt = slice*512 + tm*32;

    // ---- prefetch tm+1 M ----
    f32x4 mn0, mn1, mn2, mn3;
    if (tm < 15) {
      const float* nx = mrow + (tm+1)*32;
      mn0 = ntload4(nx);      mn1 = ntload4(nx + 8);
      mn2 = ntload4(nx + 16); mn3 = ntload4(nx + 24);
    }

    // ---- K frags (L2) ----
    short8 kb[4];
#pragma unroll
    for (int m = 0; m < 4; m++)
      kb[m] = *(const short8*)(KP + (2*m + h)*65536 + (size_t)(jt + l31)*8);

    // ---- V'/H B-frags (L2) ----
    int j8 = jt >> 3;
    const unsigned short* vbase = VP2 + (size_t)j8*512 + (dh*32 + l31)*8;
    const unsigned short* hbase = HP  + (size_t)j8*512 + (dh*32 + l31)*8;
    short8 vb1 = *(const short8*)(vbase + h*512);
    short8 vb2 = *(const short8*)(vbase + (2 + h)*512);
    short8 hb1 = *(const short8*)(hbase + h*512);
    short8 hb2 = *(const short8*)(hbase + (2 + h)*512);

    // ---- sacc = K x Q^T (lane = i, regs = j) ----
    f32x16 sacc;
    for (int r = 0; r < 16; r++) sacc[r] = 0.f;
#pragma unroll
    for (int m = 0; m < 4; m++)
      sacc = __builtin_amdgcn_mfma_f32_32x32x16_bf16(kb[m], qb[m], sacc, 0, 0, 0);

    // ---- p = exp2(s*M) (unnormalized; norm folded into V') ----
    const f32x4 mq[4] = {mc0, mc1, mc2, mc3};
    float p[16];
#pragma unroll
    for (int q = 0; q < 4; q++) {
      p[4*q+0] = fexp2(sacc[4*q+0] * mq[q][0]);
      p[4*q+1] = fexp2(sacc[4*q+1] * mq[q][1]);
      p[4*q+2] = fexp2(sacc[4*q+2] * mq[q][2]);
      p[4*q+3] = fexp2(sacc[4*q+3] * mq[q][3]);
    }
    unsigned pu[8], mw[8];
#pragma unroll
    for (int k = 0; k < 8; k++) pu[k] = cvtpk(p[2*k], p[2*k+1]);
#pragma unroll
    for (int q = 0; q < 4; q++) {
      mw[2*q]   = cvtpk(mq[q][0], mq[q][1]);
      mw[2*q+1] = cvtpk(mq[q][2], mq[q][3]);
    }

    // ---- half-swaps -> A-frag words ----
    asm volatile("v_permlane32_swap_b32 %0, %1" : "+v"(pu[0]), "+v"(pu[2]));
    asm volatile("v_permlane32_swap_b32 %0, %1" : "+v"(pu[1]), "+v"(pu[3]));
    asm volatile("v_permlane32_swap_b32 %0, %1" : "+v"(pu[4]), "+v"(pu[6]));
    asm volatile("v_permlane32_swap_b32 %0, %1" : "+v"(pu[5]), "+v"(pu[7]));
    asm volatile("v_permlane32_swap_b32 %0, %1" : "+v"(mw[0]), "+v"(mw[2]));
    asm volatile("v_permlane32_swap_b32 %0, %1" : "+v"(mw[1]), "+v"(mw[3]));
    asm volatile("v_permlane32_swap_b32 %0, %1" : "+v"(mw[4]), "+v"(mw[6]));
    asm volatile("v_permlane32_swap_b32 %0, %1" : "+v"(mw[5]), "+v"(mw[7]));

    W4 PA0, PA1, MA0, MA1;
    PA0.u[0] = pu[0]; PA0.u[1] = pu[1]; PA0.u[2] = pu[2]; PA0.u[3] = pu[3];
    PA1.u[0] = pu[4]; PA1.u[1] = pu[5]; PA1.u[2] = pu[6]; PA1.u[3] = pu[7];
    MA0.u[0] = mw[0]; MA0.u[1] = mw[1]; MA0.u[2] = mw[2]; MA0.u[3] = mw[3];
    MA1.u[0] = mw[4]; MA1.u[1] = mw[5]; MA1.u[2] = mw[6]; MA1.u[3] = mw[7];

    oacc = __builtin_amdgcn_mfma_f32_32x32x16_bf16(PA0.v, vb1, oacc, 0, 0, 0);
    oacc = __builtin_amdgcn_mfma_f32_32x32x16_bf16(PA1.v, vb2, oacc, 0, 0, 0);
    oacc = __builtin_amdgcn_mfma_f32_32x32x16_bf16(MA0.v, hb1, oacc, 0, 0, 0);
    oacc = __builtin_amdgcn_mfma_f32_32x32x16_bf16(MA1.v, hb2, oacc, 0, 0, 0);

    if (tm < 15) { mc0 = mn0; mc1 = mn1; mc2 = mn2; mc3 = mn3; }
  }

  float* obase = opart + (size_t)slice*OSZ;
#pragma unroll
  for (int r = 0; r < 16; r++) {
    int orow = i0 + iq*32 + (r&3) + 8*(r>>2) + 4*h;
    int ocol = dh*32 + l31;
    obase[(size_t)orow*64 + ocol] = oacc[r];
  }
}

// ---------------------------------------------------------------------------
// reduce: out = sum over NSL slices of opart  (float4, fully coalesced)
// ---------------------------------------------------------------------------
__global__ __launch_bounds__(256) void reduce_kernel(
    const float* __restrict__ opart, float* __restrict__ out)
{
  int e4 = blockIdx.x * blockDim.x + threadIdx.x;   // 0..131071
  const float4* p = (const float4*)opart;
  float4 a = p[e4];
#pragma unroll
  for (int s = 1; s < NSL; s++) {
    float4 b = p[(size_t)s*(OSZ/4) + e4];
    a.x += b.x; a.y += b.y; a.z += b.z; a.w += b.w;
  }
  ((float4*)out)[e4] = a;
}

// ---------------------------------------------------------------------------
extern "C" void kernel_launch(void* const* d_in, const int* in_sizes, int n_in,
                              void* d_out, int out_size, void* d_ws, size_t ws_size,
                              hipStream_t stream) {
  const float* X   = (const float*)d_in[0];
  const float* H   = (const float*)d_in[1];
  const float* M   = (const float*)d_in[2];
  const float* Qw  = (const float*)d_in[3];
  const float* Qb  = (const float*)d_in[4];
  const float* Kw  = (const float*)d_in[5];
  const float* Kb  = (const float*)d_in[6];
  const float* Vw  = (const float*)d_in[7];
  const float* Vb  = (const float*)d_in[8];
  const float* bng = (const float*)d_in[9];
  const float* bnb = (const float*)d_in[10];
  const float* bnm = (const float*)d_in[11];
  const float* bnv = (const float*)d_in[12];
  float* out = (float*)d_out;

  char* ws = (char*)d_ws;
  const size_t MB = 1024*1024;
  unsigned short* QP  = (unsigned short*)(ws);           // 1 MB
  unsigned short* KP  = (unsigned short*)(ws + 1*MB);
  unsigned short* VP  = (unsigned short*)(ws + 2*MB);
  unsigned short* HP  = (unsigned short*)(ws + 3*MB);
  unsigned short* VP2 = (unsigned short*)(ws + 4*MB);
  float* pd           = (float*)(ws + 5*MB);             // 1 MB
  float* csc          = (float*)(ws + 6*MB);             // 32 KB
  float* opart        = (float*)(ws + 7*MB);             // 32 MB (16 slices)

  qkv_kernel<<<512, 256, 0, stream>>>(X, H, Qw, Qb, Kw, Kb, Vw, Vb,
                                      bng, bnb, bnm, bnv, QP, KP, VP, HP);
  pass1_kernel<<<2048, 256, 0, stream>>>(M, QP, KP, pd);
  combine_kernel<<<32, 256, 0, stream>>>(pd, csc);
  vscale_kernel<<<256, 256, 0, stream>>>(VP, csc, VP2);
  pass2_kernel<<<2048, 256, 0, stream>>>(M, QP, KP, VP2, HP, opart);
  reduce_kernel<<<512, 256, 0, stream>>>(opart, out);
}

// Round 12
// 175.520 us; speedup vs baseline: 1.6260x; 1.6260x over previous
//
#include <hip/hip_runtime.h>
#include <hip/hip_bf16.h>
#include <math.h>

#define NN 8192
#define QSCALE (0.125f * 1.44269504088896f)   // fold 0.125 and log2(e) into Q
#define OSZ (8192*64)
#define NSL 8                                  // pass2 output slices

typedef __attribute__((ext_vector_type(8))) short short8;
typedef __attribute__((ext_vector_type(16))) float f32x16;
typedef __attribute__((ext_vector_type(4))) float f32x4;

union W4 { unsigned u[4]; short8 v; };

__device__ inline unsigned short f2bf(float x) {
  union { float f; unsigned u; } t; t.f = x;
  unsigned r = t.u + 0x7fffu + ((t.u >> 16) & 1u);
  return (unsigned short)(r >> 16);
}
__device__ inline unsigned cvtpk(float lo, float hi) {
  unsigned r;
  asm("v_cvt_pk_bf16_f32 %0, %1, %2" : "=v"(r) : "v"(lo), "v"(hi));
  return r;
}
__device__ inline float fexp2(float x) {
  float r;
  asm("v_exp_f32 %0, %1" : "=v"(r) : "v"(x));
  return r;
}
// async global -> LDS, 16B per lane; LDS dest = base + lane*16 (HW)
__device__ inline void gload16(const float* g, float* l) {
  __builtin_amdgcn_global_load_lds(
      (const __attribute__((address_space(1))) void*)g,
      (__attribute__((address_space(3))) void*)l, 16, 0, 0);
}

// ---------------------------------------------------------------------------
// Kernel 1: Q/K/V/H pre-pack.
//  QP[c8][i][e] = Q[i][c8*8+e]*QSCALE ; KP same for K
//  VP[j8][d][e] = V[j8*8+e][d] (raw) ; HP same for H
// ---------------------------------------------------------------------------
__global__ __launch_bounds__(256) void qkv_kernel(
    const float* __restrict__ X, const float* __restrict__ H,
    const float* __restrict__ Qw, const float* __restrict__ Qb,
    const float* __restrict__ Kw, const float* __restrict__ Kb,
    const float* __restrict__ Vw, const float* __restrict__ Vb,
    const float* __restrict__ bng, const float* __restrict__ bnb,
    const float* __restrict__ bnm, const float* __restrict__ bnv,
    unsigned short* __restrict__ QP, unsigned short* __restrict__ KP,
    unsigned short* __restrict__ VP, unsigned short* __restrict__ HP)
{
  int wid = (blockIdx.x * blockDim.x + threadIdx.x) >> 6; // 0..2047
  int d = threadIdx.x & 63;
  float4 w[16];

  for (int fq = 0; fq < 16; fq++) w[fq] = *(const float4*)(Qw + d*64 + fq*4);
  for (int rr = 0; rr < 4; rr++) {
    int r = wid*4 + rr;
    float a = Qb[d];
    for (int fq = 0; fq < 16; fq++) {
      float4 xv = *(const float4*)(X + r*64 + fq*4);
      a += w[fq].x*xv.x + w[fq].y*xv.y + w[fq].z*xv.z + w[fq].w*xv.w;
    }
    float s = a;
    for (int off = 32; off; off >>= 1) s += __shfl_xor(s, off);
    float mean = s * (1.f/64.f);
    float c = a - mean;
    float s2 = c*c;
    for (int off = 32; off; off >>= 1) s2 += __shfl_xor(s2, off);
    float q = c * rsqrtf(s2*(1.f/64.f) + 1e-5f);
    QP[(d>>3)*65536 + r*8 + (d&7)] = f2bf(q * QSCALE);
  }
  for (int fq = 0; fq < 16; fq++) w[fq] = *(const float4*)(Kw + d*64 + fq*4);
  for (int rr = 0; rr < 4; rr++) {
    int r = wid*4 + rr;
    float a = Kb[d];
    for (int fq = 0; fq < 16; fq++) {
      float4 hv = *(const float4*)(H + r*64 + fq*4);
      a += w[fq].x*hv.x + w[fq].y*hv.y + w[fq].z*hv.z + w[fq].w*hv.w;
    }
    float s = a;
    for (int off = 32; off; off >>= 1) s += __shfl_xor(s, off);
    float mean = s * (1.f/64.f);
    float c = a - mean;
    float s2 = c*c;
    for (int off = 32; off; off >>= 1) s2 += __shfl_xor(s2, off);
    float k = c * rsqrtf(s2*(1.f/64.f) + 1e-5f);
    KP[(d>>3)*65536 + r*8 + (d&7)] = f2bf(k);
  }
  for (int fq = 0; fq < 16; fq++) w[fq] = *(const float4*)(Vw + d*64 + fq*4);
  float bscale = rsqrtf(bnv[d] + 1e-5f) * bng[d];
  for (int rr = 0; rr < 4; rr++) {
    int r = wid*4 + rr;
    float a = Vb[d];
    for (int fq = 0; fq < 16; fq++) {
      float4 hv = *(const float4*)(H + r*64 + fq*4);
      a += w[fq].x*hv.x + w[fq].y*hv.y + w[fq].z*hv.z + w[fq].w*hv.w;
    }
    float v = (a - bnm[d]) * bscale + bnb[d];
    VP[(r>>3)*512 + d*8 + (r&7)] = f2bf(v);
    HP[(r>>3)*512 + d*8 + (r&7)] = f2bf(H[r*64 + d]);
  }
}

// ---------------------------------------------------------------------------
// pass 1 (lean): per-column sums of exp2(s*M). Plain cached M loads.
// ---------------------------------------------------------------------------
__global__ __launch_bounds__(256) void pass1_kernel(
    const float* __restrict__ M, const unsigned short* __restrict__ QP,
    const unsigned short* __restrict__ KP, float* __restrict__ pd)
{
  int tid = threadIdx.x;
  int wj = (blockIdx.x * blockDim.x + tid) >> 6;  // 0..8191
  int lane = tid & 63;
  int l31 = lane & 31, h = lane >> 5;
  int jb = wj & 255, slice = wj >> 8;             // 256 jb x 32 slices
  int j = jb*32 + l31;

  short8 kb[4];
  for (int m = 0; m < 4; m++)
    kb[m] = *(const short8*)(KP + (2*m + h)*65536 + j*8);

  float Mv[16];
  {
    int i0 = slice*8*32;
#pragma unroll
    for (int r = 0; r < 16; r++) {
      int ir = (r&3) + 8*(r>>2) + 4*h;
      Mv[r] = M[(size_t)(i0 + ir)*NN + j];
    }
  }

  float d0 = 0.f, d1 = 0.f, d2 = 0.f, d3 = 0.f;
  for (int t = 0; t < 8; t++) {
    int i0 = (slice*8 + t) * 32;
    float Mn[16];
    if (t < 7) {
      int i1 = i0 + 32;
#pragma unroll
      for (int r = 0; r < 16; r++) {
        int ir = (r&3) + 8*(r>>2) + 4*h;
        Mn[r] = M[(size_t)(i1 + ir)*NN + j];
      }
    }

    f32x16 acc;
    for (int r = 0; r < 16; r++) acc[r] = 0.f;
    for (int m = 0; m < 4; m++) {
      short8 qa = *(const short8*)(QP + (2*m + h)*65536 + (size_t)(i0 + l31)*8);
      acc = __builtin_amdgcn_mfma_f32_32x32x16_bf16(qa, kb[m], acc, 0, 0, 0);
    }

    d0 += fexp2(acc[0]*Mv[0]) + fexp2(acc[4]*Mv[4]) + fexp2(acc[8]*Mv[8])   + fexp2(acc[12]*Mv[12]);
    d1 += fexp2(acc[1]*Mv[1]) + fexp2(acc[5]*Mv[5]) + fexp2(acc[9]*Mv[9])   + fexp2(acc[13]*Mv[13]);
    d2 += fexp2(acc[2]*Mv[2]) + fexp2(acc[6]*Mv[6]) + fexp2(acc[10]*Mv[10]) + fexp2(acc[14]*Mv[14]);
    d3 += fexp2(acc[3]*Mv[3]) + fexp2(acc[7]*Mv[7]) + fexp2(acc[11]*Mv[11]) + fexp2(acc[15]*Mv[15]);

    if (t < 7) {
#pragma unroll
      for (int r = 0; r < 16; r++) Mv[r] = Mn[r];
    }
  }
  float drun = (d0 + d1) + (d2 + d3);
  drun += __shfl_xor(drun, 32);
  if (lane < 32) pd[(size_t)slice*NN + j] = drun;
}

// ---------------------------------------------------------------------------
// combine: csc[j] = alpha / D_j   (normalization folded into V)
// ---------------------------------------------------------------------------
__global__ __launch_bounds__(256) void combine_kernel(
    const float* __restrict__ pd, float* __restrict__ csc)
{
  int j = blockIdx.x * blockDim.x + threadIdx.x;
  float Dv = 0.f;
  for (int s = 0; s < 32; s++) Dv += pd[(size_t)s*NN + j];
  csc[j] = 0.1f / Dv;
}

// ---------------------------------------------------------------------------
// vscale: VP2[j8][d][e] = VP[j8][d][e] * csc[j8*8+e]
// ---------------------------------------------------------------------------
__global__ __launch_bounds__(256) void vscale_kernel(
    const unsigned short* __restrict__ VP, const float* __restrict__ csc,
    unsigned short* __restrict__ VP2)
{
  int idx = blockIdx.x * blockDim.x + threadIdx.x;   // 0..65535 = (j8, d)
  int j8 = idx >> 6;
  const unsigned short* src = VP + (size_t)idx*8;
  float c[8];
#pragma unroll
  for (int e = 0; e < 8; e++) c[e] = csc[j8*8 + e];
  unsigned short sv[8];
  *(short8*)sv = *(const short8*)src;
  float f[8];
#pragma unroll
  for (int e = 0; e < 8; e++)
    f[e] = __uint_as_float(((unsigned)sv[e]) << 16) * c[e];
  W4 o;
  o.u[0] = cvtpk(f[0], f[1]); o.u[1] = cvtpk(f[2], f[3]);
  o.u[2] = cvtpk(f[4], f[5]); o.u[3] = cvtpk(f[6], f[7]);
  *(short8*)(VP2 + (size_t)idx*8) = o.v;
}

// ---------------------------------------------------------------------------
// pass 2 (global_load_lds + XOR swizzle, m97 structure):
// per tm: issue 4 gload_lds/wave for tile tm+1 -> compute tile tm (2 ti) ->
// __syncthreads (drains vmcnt; automatic write-late). LDS tile is linear
// [64][64] f32 (gload_lds requires contiguity); source granule pre-swizzled
// g^(row&15), read applies the same XOR -> conflict-free-equivalent b128.
// Norm folded into V' -> p = exp2(s*M), no cc. Grid = 128 iblk x 8 slices.
// ---------------------------------------------------------------------------
__global__ __launch_bounds__(256) void pass2_kernel(
    const float* __restrict__ M, const unsigned short* __restrict__ QP,
    const unsigned short* __restrict__ KP, const unsigned short* __restrict__ VP2,
    const unsigned short* __restrict__ HP, float* __restrict__ opart)
{
  __shared__ __align__(16) float tile[2][64*64];

  int iblk = blockIdx.x >> 3, slice = blockIdx.x & 7;
  int i0 = iblk * 64;
  int tid = threadIdx.x;
  int lane = tid & 63, wv = tid >> 6;
  int l31 = lane & 31, h = lane >> 5;
  int iq = wv & 1, dh = wv >> 1;
  int i_g = i0 + iq*32 + l31;
  int r15 = l31 & 15;

  short8 qb[4];
#pragma unroll
  for (int m = 0; m < 4; m++)
    qb[m] = *(const short8*)(QP + (2*m + h)*65536 + (size_t)i_g*8);

  // staging geometry (per wave): rows wv*16 .. wv*16+15, 4 instr x 4 rows
  int rsub = lane >> 4;            // 0..3 row within instr group
  int gdst = lane & 15;            // dest granule (HW: base + lane*16)
  int c0base = slice*1024;

  // prologue: stage tile 0
#pragma unroll
  for (int k = 0; k < 4; k++) {
    int rloc = wv*16 + k*4 + rsub;
    int gs = gdst ^ (rloc & 15);
    gload16(M + (size_t)(i0 + rloc)*NN + c0base + gs*4,
            &tile[0][(wv*16 + k*4)*64]);
  }
  __syncthreads();

  f32x16 oacc;
  for (int r = 0; r < 16; r++) oacc[r] = 0.f;

  // KP fragment prefetch (tm0, ti0)
  short8 kcur[4];
#pragma unroll
  for (int m = 0; m < 4; m++)
    kcur[m] = *(const short8*)(KP + (2*m + h)*65536 + (size_t)(slice*1024 + l31)*8);

  for (int tm = 0; tm < 16; tm++) {
    // ---- issue async stage of tile tm+1 ----
    if (tm < 15) {
      int c0 = c0base + (tm+1)*64;
      float* dst = tile[(tm+1) & 1];
#pragma unroll
      for (int k = 0; k < 4; k++) {
        int rloc = wv*16 + k*4 + rsub;
        int gs = gdst ^ (rloc & 15);
        gload16(M + (size_t)(i0 + rloc)*NN + c0 + gs*4,
                &dst[(wv*16 + k*4)*64]);
      }
    }
    const float* mb = tile[tm & 1];
    int row = iq*32 + l31;

#pragma unroll
    for (int ti = 0; ti < 2; ti++) {
      int jloc = tm*64 + ti*32;
      int jt = slice*1024 + jloc;

      // prefetch next KP frags
      short8 knxt[4];
      {
        int jn = (jloc + 32 < 1024) ? (jt + 32) : jt;
#pragma unroll
        for (int m = 0; m < 4; m++)
          knxt[m] = *(const short8*)(KP + (2*m + h)*65536 + (size_t)(jn + l31)*8);
      }

      // V'/H B-frags (L2)
      int j8 = jt >> 3;
      const unsigned short* vbase = VP2 + (size_t)j8*512 + (dh*32 + l31)*8;
      const unsigned short* hbase = HP  + (size_t)j8*512 + (dh*32 + l31)*8;
      short8 vb1 = *(const short8*)(vbase + h*512);
      short8 vb2 = *(const short8*)(vbase + (2 + h)*512);
      short8 hb1 = *(const short8*)(hbase + h*512);
      short8 hb2 = *(const short8*)(hbase + (2 + h)*512);

      // Mv from LDS: 4 x b128 with read-side XOR (matches source swizzle)
      f32x4 mv[4];
#pragma unroll
      for (int q = 0; q < 4; q++) {
        int gr = ti*8 + 2*q + h;
        mv[q] = *(const f32x4*)&mb[row*64 + ((gr ^ r15) << 2)];
      }

      // sacc = K x Q^T (lane = i, regs = j)
      f32x16 sacc;
      for (int r = 0; r < 16; r++) sacc[r] = 0.f;
#pragma unroll
      for (int m = 0; m < 4; m++)
        sacc = __builtin_amdgcn_mfma_f32_32x32x16_bf16(kcur[m], qb[m], sacc, 0, 0, 0);

      // p = exp2(s*M) (norm in V')
      float p[16];
#pragma unroll
      for (int q = 0; q < 4; q++) {
        p[4*q+0] = fexp2(sacc[4*q+0] * mv[q][0]);
        p[4*q+1] = fexp2(sacc[4*q+1] * mv[q][1]);
        p[4*q+2] = fexp2(sacc[4*q+2] * mv[q][2]);
        p[4*q+3] = fexp2(sacc[4*q+3] * mv[q][3]);
      }
      unsigned pu[8], mw[8];
#pragma unroll
      for (int k = 0; k < 8; k++) pu[k] = cvtpk(p[2*k], p[2*k+1]);
#pragma unroll
      for (int q = 0; q < 4; q++) {
        mw[2*q]   = cvtpk(mv[q][0], mv[q][1]);
        mw[2*q+1] = cvtpk(mv[q][2], mv[q][3]);
      }

      // half-swaps -> A-frag words
      asm volatile("v_permlane32_swap_b32 %0, %1" : "+v"(pu[0]), "+v"(pu[2]));
      asm volatile("v_permlane32_swap_b32 %0, %1" : "+v"(pu[1]), "+v"(pu[3]));
      asm volatile("v_permlane32_swap_b32 %0, %1" : "+v"(pu[4]), "+v"(pu[6]));
      asm volatile("v_permlane32_swap_b32 %0, %1" : "+v"(pu[5]), "+v"(pu[7]));
      asm volatile("v_permlane32_swap_b32 %0, %1" : "+v"(mw[0]), "+v"(mw[2]));
      asm volatile("v_permlane32_swap_b32 %0, %1" : "+v"(mw[1]), "+v"(mw[3]));
      asm volatile("v_permlane32_swap_b32 %0, %1" : "+v"(mw[4]), "+v"(mw[6]));
      asm volatile("v_permlane32_swap_b32 %0, %1" : "+v"(mw[5]), "+v"(mw[7]));

      W4 PA0, PA1, MA0, MA1;
      PA0.u[0] = pu[0]; PA0.u[1] = pu[1]; PA0.u[2] = pu[2]; PA0.u[3] = pu[3];
      PA1.u[0] = pu[4]; PA1.u[1] = pu[5]; PA1.u[2] = pu[6]; PA1.u[3] = pu[7];
      MA0.u[0] = mw[0]; MA0.u[1] = mw[1]; MA0.u[2] = mw[2]; MA0.u[3] = mw[3];
      MA1.u[0] = mw[4]; MA1.u[1] = mw[5]; MA1.u[2] = mw[6]; MA1.u[3] = mw[7];

      oacc = __builtin_amdgcn_mfma_f32_32x32x16_bf16(PA0.v, vb1, oacc, 0, 0, 0);
      oacc = __builtin_amdgcn_mfma_f32_32x32x16_bf16(PA1.v, vb2, oacc, 0, 0, 0);
      oacc = __builtin_amdgcn_mfma_f32_32x32x16_bf16(MA0.v, hb1, oacc, 0, 0, 0);
      oacc = __builtin_amdgcn_mfma_f32_32x32x16_bf16(MA1.v, hb2, oacc, 0, 0, 0);

#pragma unroll
      for (int m = 0; m < 4; m++) kcur[m] = knxt[m];
    }

    __syncthreads();   // drains vmcnt: tile tm+1 ready, tile tm free
  }

  float* obase = opart + (size_t)slice*OSZ;
#pragma unroll
  for (int r = 0; r < 16; r++) {
    int orow = i0 + iq*32 + (r&3) + 8*(r>>2) + 4*h;
    int ocol = dh*32 + l31;
    obase[(size_t)orow*64 + ocol] = oacc[r];
  }
}

// ---------------------------------------------------------------------------
// reduce: out = sum over NSL slices of opart
// ---------------------------------------------------------------------------
__global__ __launch_bounds__(256) void reduce_kernel(
    const float* __restrict__ opart, float* __restrict__ out)
{
  int e4 = blockIdx.x * blockDim.x + threadIdx.x;   // 0..131071
  const float4* p = (const float4*)opart;
  float4 a = p[e4];
#pragma unroll
  for (int s = 1; s < NSL; s++) {
    float4 b = p[(size_t)s*(OSZ/4) + e4];
    a.x += b.x; a.y += b.y; a.z += b.z; a.w += b.w;
  }
  ((float4*)out)[e4] = a;
}

// ---------------------------------------------------------------------------
extern "C" void kernel_launch(void* const* d_in, const int* in_sizes, int n_in,
                              void* d_out, int out_size, void* d_ws, size_t ws_size,
                              hipStream_t stream) {
  const float* X   = (const float*)d_in[0];
  const float* H   = (const float*)d_in[1];
  const float* M   = (const float*)d_in[2];
  const float* Qw  = (const float*)d_in[3];
  const float* Qb  = (const float*)d_in[4];
  const float* Kw  = (const float*)d_in[5];
  const float* Kb  = (const float*)d_in[6];
  const float* Vw  = (const float*)d_in[7];
  const float* Vb  = (const float*)d_in[8];
  const float* bng = (const float*)d_in[9];
  const float* bnb = (const float*)d_in[10];
  const float* bnm = (const float*)d_in[11];
  const float* bnv = (const float*)d_in[12];
  float* out = (float*)d_out;

  char* ws = (char*)d_ws;
  const size_t MB = 1024*1024;
  unsigned short* QP  = (unsigned short*)(ws);           // 1 MB
  unsigned short* KP  = (unsigned short*)(ws + 1*MB);
  unsigned short* VP  = (unsigned short*)(ws + 2*MB);
  unsigned short* HP  = (unsigned short*)(ws + 3*MB);
  unsigned short* VP2 = (unsigned short*)(ws + 4*MB);
  float* pd           = (float*)(ws + 5*MB);             // 1 MB
  float* csc          = (float*)(ws + 6*MB);             // 32 KB
  float* opart        = (float*)(ws + 7*MB);             // 16 MB (8 slices)

  qkv_kernel<<<512, 256, 0, stream>>>(X, H, Qw, Qb, Kw, Kb, Vw, Vb,
                                      bng, bnb, bnm, bnv, QP, KP, VP, HP);
  pass1_kernel<<<2048, 256, 0, stream>>>(M, QP, KP, pd);
  combine_kernel<<<32, 256, 0, stream>>>(pd, csc);
  vscale_kernel<<<256, 256, 0, stream>>>(VP, csc, VP2);
  pass2_kernel<<<1024, 256, 0, stream>>>(M, QP, KP, VP2, HP, opart);
  reduce_kernel<<<512, 256, 0, stream>>>(opart, out);
}